// Round 3
// baseline (669.904 us; speedup 1.0000x reference)
//
#include <hip/hip_runtime.h>
#include <hip/hip_bf16.h>
#include <math.h>

__device__ __forceinline__ float rdlane(float v, int l) {
    return __int_as_float(__builtin_amdgcn_readlane(__float_as_int(v), l));
}

// ---------------- Kernel 1: q = x @ Wq^T ----------------
// A = x (2048 x 512) row-major, B = Wq (4096 x 512) row-major, C = q (2048 x 4096)
// 128x128 tile, 8x8 acc per thread, K-step 16.
__global__ __launch_bounds__(256) void k1_gemm(const float* __restrict__ A,
                                               const float* __restrict__ B,
                                               float* __restrict__ C) {
    __shared__ float As[16][128];
    __shared__ float Bs[16][128];
    int t  = threadIdx.x;
    int tx = t & 15, ty = t >> 4;          // tx: n-dim, ty: m-dim
    int m0 = blockIdx.y * 128, n0 = blockIdx.x * 128;
    float acc[8][8] = {};
    for (int k0 = 0; k0 < 512; k0 += 16) {
#pragma unroll
        for (int i = 0; i < 2; ++i) {
            int u   = t * 2 + i;
            int row = u >> 2;
            int kc  = (u & 3) << 2;
            float4 av = *(const float4*)&A[(m0 + row) * 512 + k0 + kc];
            float4 bv = *(const float4*)&B[(n0 + row) * 512 + k0 + kc];
            As[kc + 0][row] = av.x; As[kc + 1][row] = av.y; As[kc + 2][row] = av.z; As[kc + 3][row] = av.w;
            Bs[kc + 0][row] = bv.x; Bs[kc + 1][row] = bv.y; Bs[kc + 2][row] = bv.z; Bs[kc + 3][row] = bv.w;
        }
        __syncthreads();
#pragma unroll
        for (int kk = 0; kk < 16; ++kk) {
            float4 a0 = *(const float4*)&As[kk][ty * 8];
            float4 a1 = *(const float4*)&As[kk][ty * 8 + 4];
            float4 b0 = *(const float4*)&Bs[kk][tx * 8];
            float4 b1 = *(const float4*)&Bs[kk][tx * 8 + 4];
            float a[8] = {a0.x, a0.y, a0.z, a0.w, a1.x, a1.y, a1.z, a1.w};
            float b[8] = {b0.x, b0.y, b0.z, b0.w, b1.x, b1.y, b1.z, b1.w};
#pragma unroll
            for (int i = 0; i < 8; ++i)
#pragma unroll
                for (int j = 0; j < 8; ++j) acc[i][j] += a[i] * b[j];
        }
        __syncthreads();
    }
#pragma unroll
    for (int i = 0; i < 8; ++i) {
        int m = m0 + ty * 8 + i;
        float4 o0; o0.x = acc[i][0]; o0.y = acc[i][1]; o0.z = acc[i][2]; o0.w = acc[i][3];
        float4 o1; o1.x = acc[i][4]; o1.y = acc[i][5]; o1.z = acc[i][6]; o1.w = acc[i][7];
        *(float4*)&C[m * 4096 + n0 + tx * 8]     = o0;
        *(float4*)&C[m * 4096 + n0 + tx * 8 + 4] = o1;
    }
}

// ---------------- Kernel 2: sim + top16 + combine + top16 + softmax ----------------
// grid: 2(c) * 8(h) * 64(ntile of 16) = 1024 blocks, 256 threads.
// Wave wv: p = wv>>1 (key half / q batch row), nh = wv&1 (n sub-half, 8 rows).
// q held in registers lane-distributed along d, broadcast via v_readlane.
// Keys staged in LDS in d-chunks of 16 floats (coalesced global, padded rows).
#define KPAD 20
__global__ __launch_bounds__(256) void k2_scores(const float* __restrict__ q,
                                                 const float* __restrict__ keys,
                                                 int* __restrict__ widx,
                                                 float* __restrict__ wcoef) {
    int bid = blockIdx.x;
    int c  = bid & 1;
    int h  = (bid >> 1) & 7;
    int n0 = (bid >> 4) * 16;

    __shared__ float K_s[2][256 * KPAD];   // 40 KB
    __shared__ float sx_s[2][16][16];
    __shared__ int   ix_s[2][16][16];

    int t = threadIdx.x;
    int wv = t >> 6, ln = t & 63;
    int p  = wv >> 1;
    int nh = wv & 1;

    // q into registers: lane ln holds q[p_batch][n0+nh*8+n][ln*4 .. ln*4+3]
    float4 qreg[8];
    {
        const float* qb = &q[(size_t)(p * 1024 + n0 + nh * 8) * 4096 + c * 2048 + h * 256 + ln * 4];
#pragma unroll
        for (int n = 0; n < 8; ++n) qreg[n] = *(const float4*)&qb[(size_t)n * 4096];
    }

    float acc[8][4];
#pragma unroll
    for (int n = 0; n < 8; ++n)
#pragma unroll
        for (int j = 0; j < 4; ++j) acc[n][j] = 0.f;

    // ---- chunked score accumulation ----
    for (int ch = 0; ch < 16; ++ch) {
        __syncthreads();   // protect K_s from previous iteration's readers
        // stage: 2p x 256k x 16d = 2048 float4; 8 per thread; 64B-contiguous segments
#pragma unroll
        for (int i = 0; i < 8; ++i) {
            int v  = t + 256 * i;
            int pp = v >> 10;
            int k  = (v >> 2) & 255;
            int s  = v & 3;
            float4 kv = *(const float4*)&keys[(size_t)(((h * 256 + k) * 2) + pp) * 256 + ch * 16 + s * 4];
            *(float4*)&K_s[pp][k * KPAD + s * 4] = kv;
        }
        __syncthreads();
        // compute: lane owns keys {ln, ln+64, ln+128, ln+192} of half p
#pragma unroll
        for (int s = 0; s < 4; ++s) {
            float4 k0 = *(const float4*)&K_s[p][(ln      ) * KPAD + s * 4];
            float4 k1 = *(const float4*)&K_s[p][(ln +  64) * KPAD + s * 4];
            float4 k2 = *(const float4*)&K_s[p][(ln + 128) * KPAD + s * 4];
            float4 k3 = *(const float4*)&K_s[p][(ln + 192) * KPAD + s * 4];
            int srcl = ch * 4 + s;   // wave-uniform source lane for this d-slice
#pragma unroll
            for (int n = 0; n < 8; ++n) {
                float qx = rdlane(qreg[n].x, srcl);
                float qy = rdlane(qreg[n].y, srcl);
                float qz = rdlane(qreg[n].z, srcl);
                float qw = rdlane(qreg[n].w, srcl);
                acc[n][0] += qx * k0.x + qy * k0.y + qz * k0.z + qw * k0.w;
                acc[n][1] += qx * k1.x + qy * k1.y + qz * k1.z + qw * k1.w;
                acc[n][2] += qx * k2.x + qy * k2.y + qz * k2.z + qw * k2.w;
                acc[n][3] += qx * k3.x + qy * k3.y + qz * k3.z + qw * k3.w;
            }
        }
    }

    // ---- top-16 per (p, n) from registers; key id = ln + 64*j ----
#pragma unroll
    for (int n = 0; n < 8; ++n) {
        for (int r = 0; r < 16; ++r) {
            float bv = acc[n][0]; int bk = ln;
            if (acc[n][1] > bv) { bv = acc[n][1]; bk = ln + 64; }
            if (acc[n][2] > bv) { bv = acc[n][2]; bk = ln + 128; }
            if (acc[n][3] > bv) { bv = acc[n][3]; bk = ln + 192; }
            for (int s = 1; s < 64; s <<= 1) {
                float ov = __shfl_xor(bv, s);
                int   ok = __shfl_xor(bk, s);
                if (ov > bv || (ov == bv && ok < bk)) { bv = ov; bk = ok; }
            }
            if (ln == 0) { sx_s[p][nh * 8 + n][r] = bv; ix_s[p][nh * 8 + n][r] = bk; }
            if ((bk & 63) == ln) {
                int slot = bk >> 6;
                if      (slot == 0) acc[n][0] = -INFINITY;
                else if (slot == 1) acc[n][1] = -INFINITY;
                else if (slot == 2) acc[n][2] = -INFINITY;
                else                acc[n][3] = -INFINITY;
            }
        }
    }
    __syncthreads();

    // ---- combine 16x16, top-16, softmax: 16 n-tasks, 4 per wave ----
    for (int task = wv * 4; task < wv * 4 + 4; ++task) {
        int n = task;
        float c0, c1, c2, c3;
        {
            int tt = ln;        c0 = sx_s[0][n][tt >> 4] + sx_s[1][n][tt & 15];
            tt = ln + 64;       c1 = sx_s[0][n][tt >> 4] + sx_s[1][n][tt & 15];
            tt = ln + 128;      c2 = sx_s[0][n][tt >> 4] + sx_s[1][n][tt & 15];
            tt = ln + 192;      c3 = sx_s[0][n][tt >> 4] + sx_s[1][n][tt & 15];
        }
        float m0 = 0.f, sum_e = 0.f, my_e = 0.f;
        int my_i = 0;
        for (int r = 0; r < 16; ++r) {
            float bv = c0; int bt = ln;
            if (c1 > bv) { bv = c1; bt = ln + 64; }
            if (c2 > bv) { bv = c2; bt = ln + 128; }
            if (c3 > bv) { bv = c3; bt = ln + 192; }
            for (int s = 1; s < 64; s <<= 1) {
                float ov = __shfl_xor(bv, s);
                int   ot = __shfl_xor(bt, s);
                if (ov > bv || (ov == bv && ot < bt)) { bv = ov; bt = ot; }
            }
            if (r == 0) m0 = bv;
            float e = expf(bv - m0);
            sum_e += e;
            int i = bt >> 4, jj = bt & 15;
            int eidx = ix_s[0][n][i] * 256 + ix_s[1][n][jj];
            if (ln == r) { my_e = e; my_i = eidx; }
            if ((bt & 63) == ln) {
                int slot = bt >> 6;
                if      (slot == 0) c0 = -INFINITY;
                else if (slot == 1) c1 = -INFINITY;
                else if (slot == 2) c2 = -INFINITY;
                else                c3 = -INFINITY;
            }
        }
        if (ln < 16) {
            int ng  = n0 + n;
            int off = ((c * 1024 + ng) * 8 + h) * 16 + ln;
            wcoef[off] = my_e / sum_e;
            widx[off]  = my_i;
        }
    }
}

// ---------------- Kernel 3: gather experts, gelu, weighted mix ----------------
// one block per (c,n); 4 waves x 32 experts; x and output accum in registers
__global__ __launch_bounds__(256) void k3_experts(const float* __restrict__ x,
                                                  const float* __restrict__ w_down,
                                                  const float* __restrict__ w_up,
                                                  const int* __restrict__ widx,
                                                  const float* __restrict__ wcoef,
                                                  float* __restrict__ out) {
    int bid = blockIdx.x;
    int c = bid >> 10, n = bid & 1023;
    int t = threadIdx.x, wv = t >> 6, ln = t & 63;
    __shared__ float wacc[4][512];

    const float* xrow = &x[(c * 1024 + n) * 512];
    float xr[8], oacc[8];
    {
        float4 xa = *(const float4*)&xrow[ln * 8];
        float4 xb = *(const float4*)&xrow[ln * 8 + 4];
        xr[0] = xa.x; xr[1] = xa.y; xr[2] = xa.z; xr[3] = xa.w;
        xr[4] = xb.x; xr[5] = xb.y; xr[6] = xb.z; xr[7] = xb.w;
    }
#pragma unroll
    for (int j = 0; j < 8; ++j) oacc[j] = 0.f;

    const int base = (c * 1024 + n) * 128;  // 8 heads * 16 experts
    for (int e = wv * 32; e < wv * 32 + 32; ++e) {
        int   idx = widx[base + e];
        float wgt = wcoef[base + e];
        const float* dr = &w_down[(long)idx * 512 + ln * 8];
        float4 da = *(const float4*)&dr[0];
        float4 db = *(const float4*)&dr[4];
        float part = da.x * xr[0] + da.y * xr[1] + da.z * xr[2] + da.w * xr[3]
                   + db.x * xr[4] + db.y * xr[5] + db.z * xr[6] + db.w * xr[7];
        for (int s = 1; s < 64; s <<= 1) part += __shfl_xor(part, s);
        float hv = part;
        float coef = 0.5f * hv * (1.f + erff(hv * 0.70710678118654752f)) * wgt;
        const float* ur = &w_up[(long)idx * 512 + ln * 8];
        float4 ua = *(const float4*)&ur[0];
        float4 ub = *(const float4*)&ur[4];
        oacc[0] += coef * ua.x; oacc[1] += coef * ua.y; oacc[2] += coef * ua.z; oacc[3] += coef * ua.w;
        oacc[4] += coef * ub.x; oacc[5] += coef * ub.y; oacc[6] += coef * ub.z; oacc[7] += coef * ub.w;
    }
#pragma unroll
    for (int j = 0; j < 8; ++j) wacc[wv][ln * 8 + j] = oacc[j];
    __syncthreads();

    float* orow = &out[(c * 1024 + n) * 512];
    for (int d = t; d < 512; d += 256)
        orow[d] = wacc[0][d] + wacc[1][d] + wacc[2][d] + wacc[3][d];
}

extern "C" void kernel_launch(void* const* d_in, const int* in_sizes, int n_in,
                              void* d_out, int out_size, void* d_ws, size_t ws_size,
                              hipStream_t stream) {
    const float* x      = (const float*)d_in[0];
    const float* Wq     = (const float*)d_in[1];
    const float* keys   = (const float*)d_in[2];
    const float* w_down = (const float*)d_in[3];
    const float* w_up   = (const float*)d_in[4];
    float* out = (float*)d_out;

    char* ws = (char*)d_ws;
    float* q     = (float*)ws;                               // 2048*4096*4 = 32 MiB
    int*   widx  = (int*)(ws + 2048UL * 4096 * 4);           // 262144*4 = 1 MiB
    float* wcoef = (float*)(ws + 2048UL * 4096 * 4 + 262144UL * 4);

    k1_gemm<<<dim3(32, 16), 256, 0, stream>>>(x, Wq, q);
    k2_scores<<<1024, 256, 0, stream>>>(q, keys, widx, wcoef);
    k3_experts<<<2048, 256, 0, stream>>>(x, w_down, w_up, widx, wcoef, out);
}

// Round 4
// 652.833 us; speedup vs baseline: 1.0261x; 1.0261x over previous
//
#include <hip/hip_runtime.h>
#include <hip/hip_bf16.h>
#include <math.h>

// ---------------- Kernel 1: q = x @ Wq^T ----------------
// A = x (2048 x 512), B = Wq (4096 x 512), C = q (2048 x 4096); 128x128 tile.
__global__ __launch_bounds__(256) void k1_gemm(const float* __restrict__ A,
                                               const float* __restrict__ B,
                                               float* __restrict__ C) {
    __shared__ float As[16][128];
    __shared__ float Bs[16][128];
    int t  = threadIdx.x;
    int tx = t & 15, ty = t >> 4;
    int m0 = blockIdx.y * 128, n0 = blockIdx.x * 128;
    float acc[8][8] = {};
    for (int k0 = 0; k0 < 512; k0 += 16) {
#pragma unroll
        for (int i = 0; i < 2; ++i) {
            int u   = t * 2 + i;
            int row = u >> 2;
            int kc  = (u & 3) << 2;
            float4 av = *(const float4*)&A[(m0 + row) * 512 + k0 + kc];
            float4 bv = *(const float4*)&B[(n0 + row) * 512 + k0 + kc];
            As[kc + 0][row] = av.x; As[kc + 1][row] = av.y; As[kc + 2][row] = av.z; As[kc + 3][row] = av.w;
            Bs[kc + 0][row] = bv.x; Bs[kc + 1][row] = bv.y; Bs[kc + 2][row] = bv.z; Bs[kc + 3][row] = bv.w;
        }
        __syncthreads();
#pragma unroll
        for (int kk = 0; kk < 16; ++kk) {
            float4 a0 = *(const float4*)&As[kk][ty * 8];
            float4 a1 = *(const float4*)&As[kk][ty * 8 + 4];
            float4 b0 = *(const float4*)&Bs[kk][tx * 8];
            float4 b1 = *(const float4*)&Bs[kk][tx * 8 + 4];
            float a[8] = {a0.x, a0.y, a0.z, a0.w, a1.x, a1.y, a1.z, a1.w};
            float b[8] = {b0.x, b0.y, b0.z, b0.w, b1.x, b1.y, b1.z, b1.w};
#pragma unroll
            for (int i = 0; i < 8; ++i)
#pragma unroll
                for (int j = 0; j < 8; ++j) acc[i][j] += a[i] * b[j];
        }
        __syncthreads();
    }
#pragma unroll
    for (int i = 0; i < 8; ++i) {
        int m = m0 + ty * 8 + i;
        float4 o0; o0.x = acc[i][0]; o0.y = acc[i][1]; o0.z = acc[i][2]; o0.w = acc[i][3];
        float4 o1; o1.x = acc[i][4]; o1.y = acc[i][5]; o1.z = acc[i][6]; o1.w = acc[i][7];
        *(float4*)&C[m * 4096 + n0 + tx * 8]     = o0;
        *(float4*)&C[m * 4096 + n0 + tx * 8 + 4] = o1;
    }
}

// ---------------- Kernel 2: sim + top16 + combine + top16 + softmax ----------------
// grid: 2(c)*8(h)*64(ntile 16) = 1024 blocks, 256 threads.
// Wave wv: p = wv>>1 (key half / q batch row), nh = wv&1 (8 q rows).
// Keys staged via LDS in 8-float chunks, row stride 9 (odd -> conflict-free).
// q read from LDS by wave-uniform broadcast float4 (no conflicts, no readlane).
// T14 split: next chunk's global loads issued into regs before current compute.
#define KROW 9
__global__ __launch_bounds__(256) void k2_scores(const float* __restrict__ q,
                                                 const float* __restrict__ keys,
                                                 int* __restrict__ widx,
                                                 float* __restrict__ wcoef) {
    int bid = blockIdx.x;
    int c  = bid & 1;
    int h  = (bid >> 1) & 7;
    int n0 = (bid >> 4) * 16;

    __shared__ float q_s[2][16][256];       // 32 KB
    __shared__ float K_s[2][256 * KROW];    // 18 KB, reused as sx/ix after scores
    float (*sx_s)[16][16] = (float (*)[16][16]) & K_s[0][0];
    int   (*ix_s)[16][16] = (int (*)[16][16])(&K_s[0][0] + 2 * 16 * 16);

    int t = threadIdx.x;
    int wv = t >> 6, ln = t & 63;
    int p  = wv >> 1;
    int nh = wv & 1;

    // stage q tiles (coalesced float4)
    for (int v = t; v < 2 * 16 * 64; v += 256) {
        int pp = v >> 10; int rem = v & 1023;
        int n = rem >> 6; int dq = (rem & 63) << 2;
        float4 src = *(const float4*)&q[(size_t)((pp * 1024) + (n0 + n)) * 4096 + c * 2048 + h * 256 + dq];
        *(float4*)&q_s[pp][n][dq] = src;
    }

    float acc[8][4];
#pragma unroll
    for (int n = 0; n < 8; ++n)
#pragma unroll
        for (int j = 0; j < 4; ++j) acc[n][j] = 0.f;

    // staging indices for this thread (4 float4 per chunk)
    int v0 = t, v1 = t + 256, v2 = t + 512, v3 = t + 768;
    int pp0 = v0 >> 9, k_0 = (v0 >> 1) & 255, s0 = v0 & 1;
    int pp1 = v1 >> 9, k_1 = (v1 >> 1) & 255, s1 = v1 & 1;
    int pp2 = v2 >> 9, k_2 = (v2 >> 1) & 255, s2 = v2 & 1;
    int pp3 = v3 >> 9, k_3 = (v3 >> 1) & 255, s3 = v3 & 1;
    const float* g0 = &keys[(size_t)(((h * 256 + k_0) * 2) + pp0) * 256 + s0 * 4];
    const float* g1 = &keys[(size_t)(((h * 256 + k_1) * 2) + pp1) * 256 + s1 * 4];
    const float* g2 = &keys[(size_t)(((h * 256 + k_2) * 2) + pp2) * 256 + s2 * 4];
    const float* g3 = &keys[(size_t)(((h * 256 + k_3) * 2) + pp3) * 256 + s3 * 4];
    float* l0 = &K_s[pp0][k_0 * KROW + s0 * 4];
    float* l1 = &K_s[pp1][k_1 * KROW + s1 * 4];
    float* l2 = &K_s[pp2][k_2 * KROW + s2 * 4];
    float* l3 = &K_s[pp3][k_3 * KROW + s3 * 4];

    float4 pre0 = *(const float4*)&g0[0];
    float4 pre1 = *(const float4*)&g1[0];
    float4 pre2 = *(const float4*)&g2[0];
    float4 pre3 = *(const float4*)&g3[0];

    for (int ch = 0; ch < 32; ++ch) {
        __syncthreads();                  // previous chunk's readers done (and q_s ready at ch=0)
        *(float4*)l0 = pre0;
        *(float4*)l1 = pre1;
        *(float4*)l2 = pre2;
        *(float4*)l3 = pre3;
        __syncthreads();
        if (ch + 1 < 32) {                // issue next chunk's loads (hide under compute)
            pre0 = *(const float4*)&g0[(ch + 1) * 8];
            pre1 = *(const float4*)&g1[(ch + 1) * 8];
            pre2 = *(const float4*)&g2[(ch + 1) * 8];
            pre3 = *(const float4*)&g3[(ch + 1) * 8];
        }
#pragma unroll
        for (int s = 0; s < 2; ++s) {
            float4 k0 = *(const float4*)&K_s[p][(ln      ) * KROW + s * 4];
            float4 k1 = *(const float4*)&K_s[p][(ln +  64) * KROW + s * 4];
            float4 k2 = *(const float4*)&K_s[p][(ln + 128) * KROW + s * 4];
            float4 k3 = *(const float4*)&K_s[p][(ln + 192) * KROW + s * 4];
#pragma unroll
            for (int n = 0; n < 8; ++n) {
                float4 qv = *(const float4*)&q_s[p][nh * 8 + n][ch * 8 + s * 4];  // broadcast
                acc[n][0] += qv.x * k0.x + qv.y * k0.y + qv.z * k0.z + qv.w * k0.w;
                acc[n][1] += qv.x * k1.x + qv.y * k1.y + qv.z * k1.z + qv.w * k1.w;
                acc[n][2] += qv.x * k2.x + qv.y * k2.y + qv.z * k2.z + qv.w * k2.w;
                acc[n][3] += qv.x * k3.x + qv.y * k3.y + qv.z * k3.z + qv.w * k3.w;
            }
        }
    }
    __syncthreads();   // all K_s reads done before sx/ix alias is written

    // ---- top-16 per (p, n) from registers; key id = ln + 64*slot ----
#pragma unroll
    for (int n = 0; n < 8; ++n) {
        for (int r = 0; r < 16; ++r) {
            float bv = acc[n][0]; int bk = ln;
            if (acc[n][1] > bv) { bv = acc[n][1]; bk = ln + 64; }
            if (acc[n][2] > bv) { bv = acc[n][2]; bk = ln + 128; }
            if (acc[n][3] > bv) { bv = acc[n][3]; bk = ln + 192; }
            for (int s = 1; s < 64; s <<= 1) {
                float ov = __shfl_xor(bv, s);
                int   ok = __shfl_xor(bk, s);
                if (ov > bv || (ov == bv && ok < bk)) { bv = ov; bk = ok; }
            }
            if (ln == 0) { sx_s[p][nh * 8 + n][r] = bv; ix_s[p][nh * 8 + n][r] = bk; }
            if ((bk & 63) == ln) {
                int slot = bk >> 6;
                if      (slot == 0) acc[n][0] = -INFINITY;
                else if (slot == 1) acc[n][1] = -INFINITY;
                else if (slot == 2) acc[n][2] = -INFINITY;
                else                acc[n][3] = -INFINITY;
            }
        }
    }
    __syncthreads();

    // ---- combine 16x16, top-16, softmax: 16 n-tasks, 4 per wave ----
    for (int task = wv * 4; task < wv * 4 + 4; ++task) {
        int n = task;
        float c0, c1, c2, c3;
        {
            int tt = ln;        c0 = sx_s[0][n][tt >> 4] + sx_s[1][n][tt & 15];
            tt = ln + 64;       c1 = sx_s[0][n][tt >> 4] + sx_s[1][n][tt & 15];
            tt = ln + 128;      c2 = sx_s[0][n][tt >> 4] + sx_s[1][n][tt & 15];
            tt = ln + 192;      c3 = sx_s[0][n][tt >> 4] + sx_s[1][n][tt & 15];
        }
        float m0 = 0.f, sum_e = 0.f, my_e = 0.f;
        int my_i = 0;
        for (int r = 0; r < 16; ++r) {
            float bv = c0; int bt = ln;
            if (c1 > bv) { bv = c1; bt = ln + 64; }
            if (c2 > bv) { bv = c2; bt = ln + 128; }
            if (c3 > bv) { bv = c3; bt = ln + 192; }
            for (int s = 1; s < 64; s <<= 1) {
                float ov = __shfl_xor(bv, s);
                int   ot = __shfl_xor(bt, s);
                if (ov > bv || (ov == bv && ot < bt)) { bv = ov; bt = ot; }
            }
            if (r == 0) m0 = bv;
            float e = expf(bv - m0);
            sum_e += e;
            int i = bt >> 4, jj = bt & 15;
            int eidx = ix_s[0][n][i] * 256 + ix_s[1][n][jj];
            if (ln == r) { my_e = e; my_i = eidx; }
            if ((bt & 63) == ln) {
                int slot = bt >> 6;
                if      (slot == 0) c0 = -INFINITY;
                else if (slot == 1) c1 = -INFINITY;
                else if (slot == 2) c2 = -INFINITY;
                else                c3 = -INFINITY;
            }
        }
        if (ln < 16) {
            int ng  = n0 + n;
            int off = ((c * 1024 + ng) * 8 + h) * 16 + ln;
            wcoef[off] = my_e / sum_e;
            widx[off]  = my_i;
        }
    }
}

// ---------------- Kernel 3: gather experts, gelu, weighted mix ----------------
__global__ __launch_bounds__(256) void k3_experts(const float* __restrict__ x,
                                                  const float* __restrict__ w_down,
                                                  const float* __restrict__ w_up,
                                                  const int* __restrict__ widx,
                                                  const float* __restrict__ wcoef,
                                                  float* __restrict__ out) {
    int bid = blockIdx.x;
    int c = bid >> 10, n = bid & 1023;
    int t = threadIdx.x, wv = t >> 6, ln = t & 63;
    __shared__ float wacc[4][512];

    const float* xrow = &x[(c * 1024 + n) * 512];
    float xr[8], oacc[8];
    {
        float4 xa = *(const float4*)&xrow[ln * 8];
        float4 xb = *(const float4*)&xrow[ln * 8 + 4];
        xr[0] = xa.x; xr[1] = xa.y; xr[2] = xa.z; xr[3] = xa.w;
        xr[4] = xb.x; xr[5] = xb.y; xr[6] = xb.z; xr[7] = xb.w;
    }
#pragma unroll
    for (int j = 0; j < 8; ++j) oacc[j] = 0.f;

    const int base = (c * 1024 + n) * 128;
    for (int e = wv * 32; e < wv * 32 + 32; ++e) {
        int   idx = widx[base + e];
        float wgt = wcoef[base + e];
        const float* dr = &w_down[(long)idx * 512 + ln * 8];
        float4 da = *(const float4*)&dr[0];
        float4 db = *(const float4*)&dr[4];
        float part = da.x * xr[0] + da.y * xr[1] + da.z * xr[2] + da.w * xr[3]
                   + db.x * xr[4] + db.y * xr[5] + db.z * xr[6] + db.w * xr[7];
        for (int s = 1; s < 64; s <<= 1) part += __shfl_xor(part, s);
        float hv = part;
        float coef = 0.5f * hv * (1.f + erff(hv * 0.70710678118654752f)) * wgt;
        const float* ur = &w_up[(long)idx * 512 + ln * 8];
        float4 ua = *(const float4*)&ur[0];
        float4 ub = *(const float4*)&ur[4];
        oacc[0] += coef * ua.x; oacc[1] += coef * ua.y; oacc[2] += coef * ua.z; oacc[3] += coef * ua.w;
        oacc[4] += coef * ub.x; oacc[5] += coef * ub.y; oacc[6] += coef * ub.z; oacc[7] += coef * ub.w;
    }
#pragma unroll
    for (int j = 0; j < 8; ++j) wacc[wv][ln * 8 + j] = oacc[j];
    __syncthreads();

    float* orow = &out[(c * 1024 + n) * 512];
    for (int d = t; d < 512; d += 256)
        orow[d] = wacc[0][d] + wacc[1][d] + wacc[2][d] + wacc[3][d];
}

extern "C" void kernel_launch(void* const* d_in, const int* in_sizes, int n_in,
                              void* d_out, int out_size, void* d_ws, size_t ws_size,
                              hipStream_t stream) {
    const float* x      = (const float*)d_in[0];
    const float* Wq     = (const float*)d_in[1];
    const float* keys   = (const float*)d_in[2];
    const float* w_down = (const float*)d_in[3];
    const float* w_up   = (const float*)d_in[4];
    float* out = (float*)d_out;

    char* ws = (char*)d_ws;
    float* q     = (float*)ws;                               // 32 MiB
    int*   widx  = (int*)(ws + 2048UL * 4096 * 4);           // 1 MiB
    float* wcoef = (float*)(ws + 2048UL * 4096 * 4 + 262144UL * 4);

    k1_gemm<<<dim3(32, 16), 256, 0, stream>>>(x, Wq, q);
    k2_scores<<<1024, 256, 0, stream>>>(q, keys, widx, wcoef);
    k3_experts<<<2048, 256, 0, stream>>>(x, w_down, w_up, widx, wcoef, out);
}

// Round 5
// 451.794 us; speedup vs baseline: 1.4828x; 1.4450x over previous
//
#include <hip/hip_runtime.h>
#include <hip/hip_bf16.h>
#include <math.h>

__device__ __forceinline__ unsigned f2u(float f) {
    unsigned b = __float_as_uint(f);
    return b ^ ((unsigned)((int)b >> 31) | 0x80000000u);
}
__device__ __forceinline__ float u2f(unsigned u) {
    unsigned b = (u & 0x80000000u) ? (u ^ 0x80000000u) : ~u;
    return __uint_as_float(b);
}

// wave-level exact k=16 radix select over 256 values (4 per lane).
// Returns T = 16th-largest (as ordered uint) and kk = # of ==T to take.
__device__ __forceinline__ void radix16(unsigned u0, unsigned u1, unsigned u2, unsigned u3,
                                        unsigned& T, int& kk) {
    unsigned prefix = 0; int k = 16;
    for (int b = 31; b >= 0; --b) {
        unsigned hi = (prefix >> b) | 1u;
        int cnt = __popcll(__ballot((u0 >> b) == hi))
                + __popcll(__ballot((u1 >> b) == hi))
                + __popcll(__ballot((u2 >> b) == hi))
                + __popcll(__ballot((u3 >> b) == hi));
        if (cnt >= k) prefix |= (1u << b); else k -= cnt;
    }
    T = prefix; kk = k;
}

// ---------------- Kernel 1: q = x @ Wq^T ----------------
__global__ __launch_bounds__(256) void k1_gemm(const float* __restrict__ A,
                                               const float* __restrict__ B,
                                               float* __restrict__ C) {
    __shared__ float As[16][128];
    __shared__ float Bs[16][128];
    int t  = threadIdx.x;
    int tx = t & 15, ty = t >> 4;
    int m0 = blockIdx.y * 128, n0 = blockIdx.x * 128;
    float acc[8][8] = {};
    for (int k0 = 0; k0 < 512; k0 += 16) {
#pragma unroll
        for (int i = 0; i < 2; ++i) {
            int u   = t * 2 + i;
            int row = u >> 2;
            int kc  = (u & 3) << 2;
            float4 av = *(const float4*)&A[(m0 + row) * 512 + k0 + kc];
            float4 bv = *(const float4*)&B[(n0 + row) * 512 + k0 + kc];
            As[kc + 0][row] = av.x; As[kc + 1][row] = av.y; As[kc + 2][row] = av.z; As[kc + 3][row] = av.w;
            Bs[kc + 0][row] = bv.x; Bs[kc + 1][row] = bv.y; Bs[kc + 2][row] = bv.z; Bs[kc + 3][row] = bv.w;
        }
        __syncthreads();
#pragma unroll
        for (int kk = 0; kk < 16; ++kk) {
            float4 a0 = *(const float4*)&As[kk][ty * 8];
            float4 a1 = *(const float4*)&As[kk][ty * 8 + 4];
            float4 b0 = *(const float4*)&Bs[kk][tx * 8];
            float4 b1 = *(const float4*)&Bs[kk][tx * 8 + 4];
            float a[8] = {a0.x, a0.y, a0.z, a0.w, a1.x, a1.y, a1.z, a1.w};
            float b[8] = {b0.x, b0.y, b0.z, b0.w, b1.x, b1.y, b1.z, b1.w};
#pragma unroll
            for (int i = 0; i < 8; ++i)
#pragma unroll
                for (int j = 0; j < 8; ++j) acc[i][j] += a[i] * b[j];
        }
        __syncthreads();
    }
#pragma unroll
    for (int i = 0; i < 8; ++i) {
        int m = m0 + ty * 8 + i;
        float4 o0; o0.x = acc[i][0]; o0.y = acc[i][1]; o0.z = acc[i][2]; o0.w = acc[i][3];
        float4 o1; o1.x = acc[i][4]; o1.y = acc[i][5]; o1.z = acc[i][6]; o1.w = acc[i][7];
        *(float4*)&C[m * 4096 + n0 + tx * 8]     = o0;
        *(float4*)&C[m * 4096 + n0 + tx * 8 + 4] = o1;
    }
}

// ---------------- Kernel 2: sim + radix top16 + combine + radix top16 + softmax ----------------
#define KROW 9
__global__ __launch_bounds__(256) void k2_scores(const float* __restrict__ q,
                                                 const float* __restrict__ keys,
                                                 int* __restrict__ widx,
                                                 float* __restrict__ wcoef) {
    int bid = blockIdx.x;
    int cc = bid & 1;
    int h  = (bid >> 1) & 7;
    int n0 = (bid >> 4) * 16;

    __shared__ float q_s[2][16][256];       // 32 KB
    __shared__ float K_s[2][256 * KROW];    // 18 KB, reused as sx/ix after scores
    float (*sx_s)[16][16] = (float (*)[16][16]) & K_s[0][0];
    int   (*ix_s)[16][16] = (int (*)[16][16])(&K_s[0][0] + 2 * 16 * 16);

    int t = threadIdx.x;
    int wv = t >> 6, ln = t & 63;
    int p  = wv >> 1;
    int nh = wv & 1;
    unsigned long long lt = (1ull << ln) - 1ull;

    // stage q tiles (coalesced float4)
    for (int v = t; v < 2 * 16 * 64; v += 256) {
        int pp = v >> 10; int rem = v & 1023;
        int n = rem >> 6; int dq = (rem & 63) << 2;
        float4 src = *(const float4*)&q[(size_t)((pp * 1024) + (n0 + n)) * 4096 + cc * 2048 + h * 256 + dq];
        *(float4*)&q_s[pp][n][dq] = src;
    }

    float acc[8][4];
#pragma unroll
    for (int n = 0; n < 8; ++n)
#pragma unroll
        for (int j = 0; j < 4; ++j) acc[n][j] = 0.f;

    // staging indices (4 float4 per chunk per thread)
    int v0 = t, v1 = t + 256, v2 = t + 512, v3 = t + 768;
    int pp0 = v0 >> 9, k_0 = (v0 >> 1) & 255, s0 = v0 & 1;
    int pp1 = v1 >> 9, k_1 = (v1 >> 1) & 255, s1 = v1 & 1;
    int pp2 = v2 >> 9, k_2 = (v2 >> 1) & 255, s2 = v2 & 1;
    int pp3 = v3 >> 9, k_3 = (v3 >> 1) & 255, s3 = v3 & 1;
    const float* g0 = &keys[(size_t)(((h * 256 + k_0) * 2) + pp0) * 256 + s0 * 4];
    const float* g1 = &keys[(size_t)(((h * 256 + k_1) * 2) + pp1) * 256 + s1 * 4];
    const float* g2 = &keys[(size_t)(((h * 256 + k_2) * 2) + pp2) * 256 + s2 * 4];
    const float* g3 = &keys[(size_t)(((h * 256 + k_3) * 2) + pp3) * 256 + s3 * 4];
    float* l0 = &K_s[pp0][k_0 * KROW + s0 * 4];
    float* l1 = &K_s[pp1][k_1 * KROW + s1 * 4];
    float* l2 = &K_s[pp2][k_2 * KROW + s2 * 4];
    float* l3 = &K_s[pp3][k_3 * KROW + s3 * 4];

    float4 pre0 = *(const float4*)&g0[0];
    float4 pre1 = *(const float4*)&g1[0];
    float4 pre2 = *(const float4*)&g2[0];
    float4 pre3 = *(const float4*)&g3[0];

    for (int ch = 0; ch < 32; ++ch) {
        __syncthreads();
        *(float4*)l0 = pre0;
        *(float4*)l1 = pre1;
        *(float4*)l2 = pre2;
        *(float4*)l3 = pre3;
        __syncthreads();
        if (ch + 1 < 32) {
            pre0 = *(const float4*)&g0[(ch + 1) * 8];
            pre1 = *(const float4*)&g1[(ch + 1) * 8];
            pre2 = *(const float4*)&g2[(ch + 1) * 8];
            pre3 = *(const float4*)&g3[(ch + 1) * 8];
        }
#pragma unroll
        for (int s = 0; s < 2; ++s) {
            float4 k0 = *(const float4*)&K_s[p][(ln      ) * KROW + s * 4];
            float4 k1 = *(const float4*)&K_s[p][(ln +  64) * KROW + s * 4];
            float4 k2 = *(const float4*)&K_s[p][(ln + 128) * KROW + s * 4];
            float4 k3 = *(const float4*)&K_s[p][(ln + 192) * KROW + s * 4];
#pragma unroll
            for (int n = 0; n < 8; ++n) {
                float4 qv = *(const float4*)&q_s[p][nh * 8 + n][ch * 8 + s * 4];  // broadcast
                acc[n][0] += qv.x * k0.x + qv.y * k0.y + qv.z * k0.z + qv.w * k0.w;
                acc[n][1] += qv.x * k1.x + qv.y * k1.y + qv.z * k1.z + qv.w * k1.w;
                acc[n][2] += qv.x * k2.x + qv.y * k2.y + qv.z * k2.z + qv.w * k2.w;
                acc[n][3] += qv.x * k3.x + qv.y * k3.y + qv.z * k3.z + qv.w * k3.w;
            }
        }
    }
    __syncthreads();   // all K_s reads done before sx/ix alias is written

    // ---- top-16 per (p, n): radix select + ballot compaction (key id = ln + 64*slot) ----
#pragma unroll
    for (int n = 0; n < 8; ++n) {
        int nn = nh * 8 + n;
        unsigned u0 = f2u(acc[n][0]), u1 = f2u(acc[n][1]);
        unsigned u2 = f2u(acc[n][2]), u3 = f2u(acc[n][3]);
        unsigned T; int kk;
        radix16(u0, u1, u2, u3, T, kk);
        int base = 0;
#define TK1_GT(J, UJ, VJ) { unsigned long long m = __ballot(UJ > T);            \
        if (UJ > T) { int pos = base + __popcll(m & lt);                        \
            sx_s[p][nn][pos] = VJ; ix_s[p][nn][pos] = ln + 64 * J; }            \
        base += __popcll(m); }
        TK1_GT(0, u0, acc[n][0]); TK1_GT(1, u1, acc[n][1]);
        TK1_GT(2, u2, acc[n][2]); TK1_GT(3, u3, acc[n][3]);
#undef TK1_GT
#define TK1_EQ(J, UJ, VJ) { unsigned long long m = __ballot(UJ == T);           \
        int r = __popcll(m & lt);                                               \
        if ((UJ == T) && r < kk) { sx_s[p][nn][base + r] = VJ;                  \
            ix_s[p][nn][base + r] = ln + 64 * J; }                              \
        int cn = __popcll(m); int tk = cn < kk ? cn : kk;                       \
        base += tk; kk -= tk; }
        TK1_EQ(0, u0, acc[n][0]); TK1_EQ(1, u1, acc[n][1]);
        TK1_EQ(2, u2, acc[n][2]); TK1_EQ(3, u3, acc[n][3]);
#undef TK1_EQ
    }
    __syncthreads();

    // ---- combine 16x16, radix top-16, softmax: 4 tasks per wave ----
    for (int task = wv * 4; task < wv * 4 + 4; ++task) {
        int n = task;
        int t0 = ln, t1 = ln + 64, t2 = ln + 128, t3 = ln + 192;
        float vc0 = sx_s[0][n][t0 >> 4] + sx_s[1][n][t0 & 15];
        float vc1 = sx_s[0][n][t1 >> 4] + sx_s[1][n][t1 & 15];
        float vc2 = sx_s[0][n][t2 >> 4] + sx_s[1][n][t2 & 15];
        float vc3 = sx_s[0][n][t3 >> 4] + sx_s[1][n][t3 & 15];
        unsigned u0 = f2u(vc0), u1 = f2u(vc1), u2 = f2u(vc2), u3 = f2u(vc3);
        unsigned T; int kk;
        radix16(u0, u1, u2, u3, T, kk);
        float Tf = u2f(T);

        bool w0 = u0 > T, w1 = u1 > T, w2 = u2 > T, w3 = u3 > T;
        int q0 = 0, q1 = 0, q2 = 0, q3 = 0;
        int base = 0;
        { unsigned long long m = __ballot(w0); q0 = base + __popcll(m & lt); base += __popcll(m); }
        { unsigned long long m = __ballot(w1); q1 = base + __popcll(m & lt); base += __popcll(m); }
        { unsigned long long m = __ballot(w2); q2 = base + __popcll(m & lt); base += __popcll(m); }
        { unsigned long long m = __ballot(w3); q3 = base + __popcll(m & lt); base += __popcll(m); }
#define CMB_EQ(UJ, WJ, QJ) { unsigned long long m = __ballot(UJ == T);          \
        int r = __popcll(m & lt);                                               \
        if ((UJ == T) && r < kk) { WJ = true; QJ = base + r; }                  \
        int cn = __popcll(m); int tk = cn < kk ? cn : kk;                       \
        base += tk; kk -= tk; }
        CMB_EQ(u0, w0, q0); CMB_EQ(u1, w1, q1); CMB_EQ(u2, w2, q2); CMB_EQ(u3, w3, q3);
#undef CMB_EQ

        // exp shifted by T (winners satisfy v - Tf >= 0, small spread)
        float e0 = 0.f, e1 = 0.f, e2 = 0.f, e3 = 0.f;
        int id0 = 0, id1 = 0, id2 = 0, id3 = 0;
        float es = 0.f;
        if (w0) { e0 = __expf(vc0 - Tf); es += e0; id0 = ix_s[0][n][t0 >> 4] * 256 + ix_s[1][n][t0 & 15]; }
        if (w1) { e1 = __expf(vc1 - Tf); es += e1; id1 = ix_s[0][n][t1 >> 4] * 256 + ix_s[1][n][t1 & 15]; }
        if (w2) { e2 = __expf(vc2 - Tf); es += e2; id2 = ix_s[0][n][t2 >> 4] * 256 + ix_s[1][n][t2 & 15]; }
        if (w3) { e3 = __expf(vc3 - Tf); es += e3; id3 = ix_s[0][n][t3 >> 4] * 256 + ix_s[1][n][t3 & 15]; }
        for (int s = 1; s < 64; s <<= 1) es += __shfl_xor(es, s);
        float inv = 1.f / es;

        int off = ((cc * 1024 + n0 + n) * 8 + h) * 16;
        if (w0) { wcoef[off + q0] = e0 * inv; widx[off + q0] = id0; }
        if (w1) { wcoef[off + q1] = e1 * inv; widx[off + q1] = id1; }
        if (w2) { wcoef[off + q2] = e2 * inv; widx[off + q2] = id2; }
        if (w3) { wcoef[off + q3] = e3 * inv; widx[off + q3] = id3; }
    }
}

// ---------------- Kernel 3: gather experts, gelu, weighted mix ----------------
__global__ __launch_bounds__(256) void k3_experts(const float* __restrict__ x,
                                                  const float* __restrict__ w_down,
                                                  const float* __restrict__ w_up,
                                                  const int* __restrict__ widx,
                                                  const float* __restrict__ wcoef,
                                                  float* __restrict__ out) {
    int bid = blockIdx.x;
    int c = bid >> 10, n = bid & 1023;
    int t = threadIdx.x, wv = t >> 6, ln = t & 63;
    __shared__ float wacc[4][512];

    const float* xrow = &x[(c * 1024 + n) * 512];
    float xr[8], oacc[8];
    {
        float4 xa = *(const float4*)&xrow[ln * 8];
        float4 xb = *(const float4*)&xrow[ln * 8 + 4];
        xr[0] = xa.x; xr[1] = xa.y; xr[2] = xa.z; xr[3] = xa.w;
        xr[4] = xb.x; xr[5] = xb.y; xr[6] = xb.z; xr[7] = xb.w;
    }
#pragma unroll
    for (int j = 0; j < 8; ++j) oacc[j] = 0.f;

    const int base = (c * 1024 + n) * 128;
    for (int e = wv * 32; e < wv * 32 + 32; ++e) {
        int   idx = widx[base + e];
        float wgt = wcoef[base + e];
        const float* dr = &w_down[(long)idx * 512 + ln * 8];
        float4 da = *(const float4*)&dr[0];
        float4 db = *(const float4*)&dr[4];
        float part = da.x * xr[0] + da.y * xr[1] + da.z * xr[2] + da.w * xr[3]
                   + db.x * xr[4] + db.y * xr[5] + db.z * xr[6] + db.w * xr[7];
        for (int s = 1; s < 64; s <<= 1) part += __shfl_xor(part, s);
        float hv = part;
        float coef = 0.5f * hv * (1.f + erff(hv * 0.70710678118654752f)) * wgt;
        const float* ur = &w_up[(long)idx * 512 + ln * 8];
        float4 ua = *(const float4*)&ur[0];
        float4 ub = *(const float4*)&ur[4];
        oacc[0] += coef * ua.x; oacc[1] += coef * ua.y; oacc[2] += coef * ua.z; oacc[3] += coef * ua.w;
        oacc[4] += coef * ub.x; oacc[5] += coef * ub.y; oacc[6] += coef * ub.z; oacc[7] += coef * ub.w;
    }
#pragma unroll
    for (int j = 0; j < 8; ++j) wacc[wv][ln * 8 + j] = oacc[j];
    __syncthreads();

    float* orow = &out[(c * 1024 + n) * 512];
    for (int d = t; d < 512; d += 256)
        orow[d] = wacc[0][d] + wacc[1][d] + wacc[2][d] + wacc[3][d];
}

extern "C" void kernel_launch(void* const* d_in, const int* in_sizes, int n_in,
                              void* d_out, int out_size, void* d_ws, size_t ws_size,
                              hipStream_t stream) {
    const float* x      = (const float*)d_in[0];
    const float* Wq     = (const float*)d_in[1];
    const float* keys   = (const float*)d_in[2];
    const float* w_down = (const float*)d_in[3];
    const float* w_up   = (const float*)d_in[4];
    float* out = (float*)d_out;

    char* ws = (char*)d_ws;
    float* q     = (float*)ws;                               // 32 MiB
    int*   widx  = (int*)(ws + 2048UL * 4096 * 4);           // 1 MiB
    float* wcoef = (float*)(ws + 2048UL * 4096 * 4 + 262144UL * 4);

    k1_gemm<<<dim3(32, 16), 256, 0, stream>>>(x, Wq, q);
    k2_scores<<<1024, 256, 0, stream>>>(q, keys, widx, wcoef);
    k3_experts<<<2048, 256, 0, stream>>>(x, w_down, w_up, widx, wcoef, out);
}